// Round 2
// baseline (912.552 us; speedup 1.0000x reference)
//
#include <hip/hip_runtime.h>
#include <hip/hip_bf16.h>

// ROUND 2: BISECTION PROBE. Kernels identical to round 1 (passed, 641 us).
// kernel_launch runs the full 6-kernel sequence TWICE (all kernels are
// idempotent pure functions of d_in / earlier-stage ws buffers), so
//   dur2 = OH + 2*S  =>  S = dur2 - 641, OH = 2*641 - dur2
// splitting harness fixed overhead (OH) from kernel cost (S).

typedef __attribute__((ext_vector_type(8))) short s8v;
typedef __attribute__((ext_vector_type(4))) float f4v;
typedef unsigned short u16;

__device__ __forceinline__ unsigned short f2bf(float x) {
    union { float f; unsigned u; } v; v.f = x;
    unsigned r = v.u + 0x7fffu + ((v.u >> 16) & 1u);
    return (unsigned short)(r >> 16);
}
__device__ __forceinline__ float bf2f(unsigned short b) {
    union { unsigned u; float f; } v; v.u = ((unsigned)b) << 16;
    return v.f;
}
__device__ __forceinline__ float sigmoidf_(float x) {
    return 1.0f / (1.0f + __expf(-x));
}
__device__ __forceinline__ f4v mfma16(s8v a, s8v b, f4v c) {
    return __builtin_amdgcn_mfma_f32_16x16x32_bf16(a, b, c, 0, 0, 0);
}
__device__ __forceinline__ s8v load_wfrag(const float* __restrict__ p) {
    float4 a = *(const float4*)p;
    float4 b = *(const float4*)(p + 4);
    s8v r;
    r[0] = (short)f2bf(a.x); r[1] = (short)f2bf(a.y);
    r[2] = (short)f2bf(a.z); r[3] = (short)f2bf(a.w);
    r[4] = (short)f2bf(b.x); r[5] = (short)f2bf(b.y);
    r[6] = (short)f2bf(b.z); r[7] = (short)f2bf(b.w);
    return r;
}

__device__ __forceinline__ void ln_stage(const float* __restrict__ Xrows,
                                         const float* __restrict__ ln_w,
                                         u16* __restrict__ A, int tid) {
    const int row = tid >> 1, half = tid & 1;
    const float4* xp = (const float4*)(Xrows + (size_t)row * 128 + half * 64);
    float xv[64];
#pragma unroll
    for (int i = 0; i < 16; i++) {
        float4 t = xp[i];
        xv[i*4+0] = t.x; xv[i*4+1] = t.y; xv[i*4+2] = t.z; xv[i*4+3] = t.w;
    }
    float s1 = 0.f, s2 = 0.f;
#pragma unroll
    for (int i = 0; i < 64; i++) { s1 += xv[i]; s2 += xv[i] * xv[i]; }
    s1 += __shfl_xor(s1, 1);
    s2 += __shfl_xor(s2, 1);
    float m = s1 * (1.0f / 128.0f);
    float var = s2 * (1.0f / 128.0f) - m * m;
    float rstd = rsqrtf(var + 1e-5f);
    const float4* wp = (const float4*)(ln_w + half * 64);
    u16* arow = A + row * 136 + half * 64;
#pragma unroll
    for (int i = 0; i < 16; i++) {
        float4 w = wp[i];
        ushort4 o;
        o.x = f2bf((xv[i*4+0] - m) * rstd * w.x);
        o.y = f2bf((xv[i*4+1] - m) * rstd * w.y);
        o.z = f2bf((xv[i*4+2] - m) * rstd * w.z);
        o.w = f2bf((xv[i*4+3] - m) * rstd * w.w);
        *(ushort4*)(arow + i * 4) = o;
    }
}

__global__ __launch_bounds__(256) void k_zproj(
    const float* __restrict__ z, const float* __restrict__ ln_w,
    const float* __restrict__ gl1_w, const float* __restrict__ l1_w, const float* __restrict__ l1_b,
    const float* __restrict__ gl2_w, const float* __restrict__ l2_w, const float* __restrict__ l2_b,
    const float* __restrict__ eg_w, const float* __restrict__ eg_b,
    const float* __restrict__ z_mask,
    u16* __restrict__ ab1, u16* __restrict__ ab2, u16* __restrict__ g)
{
    __shared__ u16 A[128 * 136];
    __shared__ float zms[128];
    const int tid = threadIdx.x;
    const int lane = tid & 63, wave = tid >> 6;
    const int quad = lane >> 4, l15 = lane & 15;
    const int np = blockIdx.x;

    ln_stage(z + (size_t)np * 128 * 128, ln_w, A, tid);
    if (tid < 128) zms[tid] = z_mask[np * 128 + tid];
    __syncthreads();

    s8v bfr[4][4];
#pragma unroll
    for (int nt = 0; nt < 4; nt++) {
        int n = wave * 64 + nt * 16 + l15;
        const float* wr;
        if (n < 32)       wr = gl1_w + n * 128;
        else if (n < 64)  wr = l1_w  + (n - 32) * 128;
        else if (n < 96)  wr = gl2_w + (n - 64) * 128;
        else if (n < 128) wr = l2_w  + (n - 96) * 128;
        else              wr = eg_w  + (n - 128) * 128;
#pragma unroll
        for (int kt = 0; kt < 4; kt++)
            bfr[nt][kt] = load_wfrag(wr + kt * 32 + quad * 8);
    }

    f4v acc[8][4];
#pragma unroll
    for (int mt = 0; mt < 8; mt++)
#pragma unroll
        for (int nt = 0; nt < 4; nt++)
            acc[mt][nt] = (f4v){0.f, 0.f, 0.f, 0.f};

#pragma unroll
    for (int kt = 0; kt < 4; kt++) {
#pragma unroll
        for (int mt = 0; mt < 8; mt++) {
            s8v af = *(const s8v*)(A + (mt * 16 + l15) * 136 + kt * 32 + quad * 8);
#pragma unroll
            for (int nt = 0; nt < 4; nt++)
                acc[mt][nt] = mfma16(af, bfr[nt][kt], acc[mt][nt]);
        }
    }

    if (wave < 2) {
        u16* dst = (wave == 0) ? ab1 : ab2;
        const float* bias = (wave == 0) ? l1_b : l2_b;
#pragma unroll
        for (int mt = 0; mt < 8; mt++) {
            int j0 = mt * 16 + quad * 4;
#pragma unroll
            for (int cp = 0; cp < 2; cp++) {
                int c = cp * 16 + l15;
                float bb = bias[c];
                ushort4 o;
#pragma unroll
                for (int r = 0; r < 4; r++) {
                    float a0 = acc[mt][cp][r];
                    float a1 = acc[mt][cp + 2][r];
                    float v = sigmoidf_(a0) * (a1 + bb) * zms[j0 + r];
                    ((u16*)&o)[r] = f2bf(v);
                }
                *(ushort4*)(dst + (size_t)c * 98304 + np * 128 + j0) = o;
            }
        }
    } else {
        int ebase = (wave - 2) * 64;
#pragma unroll
        for (int mt = 0; mt < 8; mt++) {
            int j0 = mt * 16 + quad * 4;
#pragma unroll
            for (int nt = 0; nt < 4; nt++) {
                int e = ebase + nt * 16 + l15;
                float eb = eg_b[e];
#pragma unroll
                for (int r = 0; r < 4; r++) {
                    float v = sigmoidf_(acc[mt][nt][r] + eb);
                    g[((size_t)np * 128 + j0 + r) * 128 + e] = f2bf(v);
                }
            }
        }
    }
}

__global__ __launch_bounds__(256) void k_proj64(
    const float* __restrict__ X, const float* __restrict__ ln_w,
    const float* __restrict__ Wg, const float* __restrict__ Wl, const float* __restrict__ lb,
    u16* __restrict__ out, int nrows)
{
    __shared__ u16 A[128 * 136];
    const int tid = threadIdx.x;
    const int lane = tid & 63, wave = tid >> 6;
    const int quad = lane >> 4, l15 = lane & 15;
    const size_t rowbase = (size_t)blockIdx.x * 128;

    ln_stage(X + rowbase * 128, ln_w, A, tid);
    __syncthreads();

    s8v bfr[4][4];
#pragma unroll
    for (int nt = 0; nt < 4; nt++) {
        const float* wr = (nt < 2) ? (Wg + (nt * 16 + l15) * 128)
                                   : (Wl + ((nt - 2) * 16 + l15) * 128);
#pragma unroll
        for (int kt = 0; kt < 4; kt++)
            bfr[nt][kt] = load_wfrag(wr + kt * 32 + quad * 8);
    }

    f4v acc[2][4];
#pragma unroll
    for (int mt = 0; mt < 2; mt++)
#pragma unroll
        for (int nt = 0; nt < 4; nt++)
            acc[mt][nt] = (f4v){0.f, 0.f, 0.f, 0.f};

#pragma unroll
    for (int kt = 0; kt < 4; kt++) {
#pragma unroll
        for (int mt = 0; mt < 2; mt++) {
            s8v af = *(const s8v*)(A + (wave * 32 + mt * 16 + l15) * 136 + kt * 32 + quad * 8);
#pragma unroll
            for (int nt = 0; nt < 4; nt++)
                acc[mt][nt] = mfma16(af, bfr[nt][kt], acc[mt][nt]);
        }
    }

#pragma unroll
    for (int mt = 0; mt < 2; mt++) {
        int k0 = wave * 32 + mt * 16 + quad * 4;
#pragma unroll
        for (int cp = 0; cp < 2; cp++) {
            int c = cp * 16 + l15;
            float bb = lb[c];
            ushort4 o;
#pragma unroll
            for (int r = 0; r < 4; r++) {
                float v = sigmoidf_(acc[mt][cp][r]) * (acc[mt][cp + 2][r] + bb);
                ((u16*)&o)[r] = f2bf(v);
            }
            *(ushort4*)(out + (size_t)c * nrows + rowbase + k0) = o;
        }
    }
}

__global__ __launch_bounds__(256) void k_transpose_ab1(
    const u16* __restrict__ src, u16* __restrict__ dst)
{
    __shared__ u16 T[128 * 129];
    const int c = blockIdx.y;
    const int np0 = blockIdx.x * 128;
    const int tid = threadIdx.x;
    const size_t sbase = (size_t)c * 98304;
    for (int idx = tid; idx < 16384; idx += 256) {
        int r = idx >> 7, j = idx & 127;
        T[j * 129 + r] = src[sbase + (size_t)(np0 + r) * 128 + j];
    }
    __syncthreads();
    for (int idx = tid; idx < 16384; idx += 256) {
        int j = idx >> 7, r = idx & 127;
        dst[sbase + (size_t)j * 768 + np0 + r] = T[j * 129 + r];
    }
}

__global__ __launch_bounds__(256) void k_block(
    const u16* __restrict__ ppc, const u16* __restrict__ ab1T,
    const u16* __restrict__ ab2, const u16* __restrict__ cpcT,
    float* __restrict__ blk)
{
    __shared__ u16 As[128 * 72];
    __shared__ u16 Bs[128 * 72];
    const int tid = threadIdx.x;
    const int lane = tid & 63, wave = tid >> 6;
    const int quad = lane >> 4, l15 = lane & 15;
    const int it = blockIdx.x;
    const int c = blockIdx.y;
    const int i0 = it * 128;
    const int mh = (wave >> 1) * 64, nh = (wave & 1) * 64;

    f4v acc[4][4];
#pragma unroll
    for (int mt = 0; mt < 4; mt++)
#pragma unroll
        for (int nt = 0; nt < 4; nt++)
            acc[mt][nt] = (f4v){0.f, 0.f, 0.f, 0.f};

    auto stage = [&](const u16* Ab, int astride, const u16* Bb, int bstride, int kb) {
        int row = tid >> 1, half = tid & 1;
        const u16* pa = Ab + (size_t)row * astride + kb + half * 32;
        const u16* pb = Bb + (size_t)row * bstride + kb + half * 32;
        u16* da = As + row * 72 + half * 32;
        u16* db = Bs + row * 72 + half * 32;
#pragma unroll
        for (int q = 0; q < 4; q++) {
            *(uint4*)(da + q * 8) = *(const uint4*)(pa + q * 8);
            *(uint4*)(db + q * 8) = *(const uint4*)(pb + q * 8);
        }
    };
    auto compute = [&]() {
#pragma unroll
        for (int kt = 0; kt < 2; kt++) {
            s8v af[4], bf[4];
#pragma unroll
            for (int mt = 0; mt < 4; mt++)
                af[mt] = *(const s8v*)(As + (mh + mt * 16 + l15) * 72 + kt * 32 + quad * 8);
#pragma unroll
            for (int nt = 0; nt < 4; nt++)
                bf[nt] = *(const s8v*)(Bs + (nh + nt * 16 + l15) * 72 + kt * 32 + quad * 8);
#pragma unroll
            for (int mt = 0; mt < 4; mt++)
#pragma unroll
                for (int nt = 0; nt < 4; nt++)
                    acc[mt][nt] = mfma16(af[mt], bf[nt], acc[mt][nt]);
        }
    };

    const u16* Ab1 = ppc + (size_t)c * 589824 + (size_t)i0 * 768;
    const u16* Bb1 = ab1T + (size_t)c * 98304;
    for (int kb = 0; kb < 768; kb += 64) {
        stage(Ab1, 768, Bb1, 768, kb);
        __syncthreads();
        compute();
        __syncthreads();
    }
    const u16* Ab2 = ab2 + (size_t)c * 98304 + (size_t)i0 * 128;
    const u16* Bb2 = cpcT + (size_t)c * 16384;
    for (int kb = 0; kb < 128; kb += 64) {
        stage(Ab2, 128, Bb2, 128, kb);
        __syncthreads();
        compute();
        __syncthreads();
    }

    float* ob = blk + (size_t)c * 98304;
#pragma unroll
    for (int mt = 0; mt < 4; mt++) {
#pragma unroll
        for (int nt = 0; nt < 4; nt++) {
            int jj = nh + nt * 16 + l15;
#pragma unroll
            for (int r = 0; r < 4; r++) {
                int row = i0 + mh + mt * 16 + quad * 4 + r;
                ob[(size_t)row * 128 + jj] = acc[mt][nt][r];
            }
        }
    }
}

__global__ __launch_bounds__(256) void k_final(
    const float* __restrict__ blk, const u16* __restrict__ g,
    const float* __restrict__ z_mask, const float* __restrict__ lnc_w,
    const float* __restrict__ las_w, const float* __restrict__ las_b,
    float* __restrict__ out)
{
    __shared__ float vals[128 * 33];
    __shared__ u16 Abf[128 * 40];
    __shared__ float zms[128];
    __shared__ float lncs[32];
    const int tid = threadIdx.x;
    const int lane = tid & 63, wave = tid >> 6;
    const int quad = lane >> 4, l15 = lane & 15;
    const int np = blockIdx.x;

    for (int idx = tid; idx < 4096; idx += 256) {
        int c = idx >> 7, j = idx & 127;
        vals[j * 33 + c] = blk[(size_t)c * 98304 + np * 128 + j];
    }
    if (tid < 128) zms[tid] = z_mask[np * 128 + tid];
    if (tid < 32) lncs[tid] = lnc_w[tid];
    __syncthreads();

    if (tid < 128) {
        int j = tid;
        float s1 = 0.f, s2 = 0.f;
#pragma unroll
        for (int c = 0; c < 32; c++) { float x = vals[j * 33 + c]; s1 += x; s2 += x * x; }
        float m = s1 * (1.f / 32.f);
        float v = s2 * (1.f / 32.f) - m * m;
        float rstd = rsqrtf(v + 1e-5f);
#pragma unroll
        for (int c = 0; c < 32; c++)
            Abf[j * 40 + c] = f2bf((vals[j * 33 + c] - m) * rstd * lncs[c]);
    }
    __syncthreads();

    s8v bfrg[8];
#pragma unroll
    for (int nt = 0; nt < 8; nt++) {
        int e = nt * 16 + l15;
        bfrg[nt] = load_wfrag(las_w + e * 32 + quad * 8);
    }
    f4v acc[2][8];
#pragma unroll
    for (int mt = 0; mt < 2; mt++)
#pragma unroll
        for (int nt = 0; nt < 8; nt++)
            acc[mt][nt] = (f4v){0.f, 0.f, 0.f, 0.f};
#pragma unroll
    for (int mt = 0; mt < 2; mt++) {
        s8v af = *(const s8v*)(Abf + (wave * 32 + mt * 16 + l15) * 40 + quad * 8);
#pragma unroll
        for (int nt = 0; nt < 8; nt++)
            acc[mt][nt] = mfma16(af, bfrg[nt], acc[mt][nt]);
    }

#pragma unroll
    for (int mt = 0; mt < 2; mt++) {
        int jb = wave * 32 + mt * 16 + quad * 4;
#pragma unroll
        for (int nt = 0; nt < 8; nt++) {
            int e = nt * 16 + l15;
            float eb = las_b[e];
#pragma unroll
            for (int r = 0; r < 4; r++) {
                int j = jb + r;
                float gv = bf2f(g[((size_t)np * 128 + j) * 128 + e]);
                out[((size_t)np * 128 + j) * 128 + e] = gv * (acc[mt][nt][r] + eb) * zms[j];
            }
        }
    }
}

extern "C" void kernel_launch(void* const* d_in, const int* in_sizes, int n_in,
                              void* d_out, int out_size, void* d_ws, size_t ws_size,
                              hipStream_t stream)
{
    const float* z     = (const float*)d_in[0];
    const float* pp    = (const float*)d_in[1];
    const float* cp    = (const float*)d_in[2];
    const float* zm    = (const float*)d_in[3];
    const float* ln_w  = (const float*)d_in[4];
    const float* lnc_w = (const float*)d_in[5];
    const float* gl1_w = (const float*)d_in[6];
    const float* gl2_w = (const float*)d_in[7];
    const float* l1_w  = (const float*)d_in[8];
    const float* l1_b  = (const float*)d_in[9];
    const float* l2_w  = (const float*)d_in[10];
    const float* l2_b  = (const float*)d_in[11];
    const float* eg_w  = (const float*)d_in[12];
    const float* eg_b  = (const float*)d_in[13];
    const float* las_w = (const float*)d_in[14];
    const float* las_b = (const float*)d_in[15];
    float* out = (float*)d_out;

    char* w = (char*)d_ws;
    u16* ppc  = (u16*)w;  w += (size_t)32 * 768 * 768 * 2;
    u16* ab1t = (u16*)w;  w += (size_t)32 * 768 * 128 * 2;
    u16* ab1T = (u16*)w;  w += (size_t)32 * 128 * 768 * 2;
    u16* ab2  = (u16*)w;  w += (size_t)32 * 768 * 128 * 2;
    u16* cpcT = (u16*)w;  w += (size_t)32 * 128 * 128 * 2;
    u16* g    = (u16*)w;  w += (size_t)768 * 128 * 128 * 2;
    float* blk = (float*)w;

    // Bisection: run the whole pipeline twice (idempotent).
    for (int rep = 0; rep < 2; rep++) {
        k_zproj<<<768, 256, 0, stream>>>(z, ln_w, gl1_w, l1_w, l1_b, gl2_w, l2_w, l2_b,
                                         eg_w, eg_b, zm, ab1t, ab2, g);
        k_proj64<<<4608, 256, 0, stream>>>(pp, ln_w, gl2_w, l2_w, l2_b, ppc, 589824);
        k_proj64<<<128, 256, 0, stream>>>(cp, ln_w, gl1_w, l1_w, l1_b, cpcT, 16384);
        dim3 gt(6, 32);
        k_transpose_ab1<<<gt, 256, 0, stream>>>(ab1t, ab1T);
        dim3 gb(6, 32);
        k_block<<<gb, 256, 0, stream>>>(ppc, ab1T, ab2, cpcT, blk);
        k_final<<<768, 256, 0, stream>>>(blk, g, zm, lnc_w, las_w, las_b, out);
    }
}

// Round 3
// 585.877 us; speedup vs baseline: 1.5576x; 1.5576x over previous
//
#include <hip/hip_runtime.h>
#include <hip/hip_bf16.h>

// Round 3: S=271us measured (OH=371us fixed harness cost inside timed region).
// Changes vs round 1: coalesced LN (32 lanes/row), prepped bf16 weights,
// bf16 blk, LDS-staged g in k_final, merged cp+transpose, vectorized transpose.

typedef __attribute__((ext_vector_type(8))) short s8v;
typedef __attribute__((ext_vector_type(4))) float f4v;
typedef unsigned short u16;

__device__ __forceinline__ unsigned short f2bf(float x) {
    union { float f; unsigned u; } v; v.f = x;
    unsigned r = v.u + 0x7fffu + ((v.u >> 16) & 1u);
    return (unsigned short)(r >> 16);
}
__device__ __forceinline__ float bf2f(unsigned short b) {
    union { unsigned u; float f; } v; v.u = ((unsigned)b) << 16;
    return v.f;
}
__device__ __forceinline__ float sigmoidf_(float x) {
    return 1.0f / (1.0f + __expf(-x));
}
__device__ __forceinline__ f4v mfma16(s8v a, s8v b, f4v c) {
    return __builtin_amdgcn_mfma_f32_16x16x32_bf16(a, b, c, 0, 0, 0);
}

// Coalesced LayerNorm: 128 rows x 128 cols fp32 -> bf16 LDS A[128][136].
// 32 lanes per row, float4 per lane; wave reads 2 contiguous rows (1KB/instr).
__device__ __forceinline__ void ln_stage_c(const float* __restrict__ Xrows,
                                           const float* __restrict__ ln_w,
                                           u16* __restrict__ A, int tid) {
    const int sub = tid >> 5;          // 0..7: row within group of 8
    const int c4 = (tid & 31) * 4;     // column base
    const float4 w4 = *(const float4*)(ln_w + c4);
#pragma unroll
    for (int p = 0; p < 16; p++) {
        const int row = p * 8 + sub;
        float4 x = *(const float4*)(Xrows + (size_t)row * 128 + c4);
        float s1 = x.x + x.y + x.z + x.w;
        float s2 = x.x * x.x + x.y * x.y + x.z * x.z + x.w * x.w;
#pragma unroll
        for (int m = 1; m <= 16; m <<= 1) {
            s1 += __shfl_xor(s1, m);
            s2 += __shfl_xor(s2, m);
        }
        float mean = s1 * (1.f / 128.f);
        float var = s2 * (1.f / 128.f) - mean * mean;
        float rstd = rsqrtf(var + 1e-5f);
        ushort4 o;
        o.x = f2bf((x.x - mean) * rstd * w4.x);
        o.y = f2bf((x.y - mean) * rstd * w4.y);
        o.z = f2bf((x.z - mean) * rstd * w4.z);
        o.w = f2bf((x.w - mean) * rstd * w4.w);
        *(ushort4*)(A + row * 136 + c4) = o;
    }
}

// ---- prep: fp32 weights -> bf16 row-major. wcat rows: gl1|l1|gl2|l2|eg (256x128),
// lasbf: 128x32.
__global__ __launch_bounds__(256) void k_prep(
    const float* __restrict__ gl1_w, const float* __restrict__ l1_w,
    const float* __restrict__ gl2_w, const float* __restrict__ l2_w,
    const float* __restrict__ eg_w, const float* __restrict__ las_w,
    u16* __restrict__ wcat, u16* __restrict__ lasbf)
{
    int idx = blockIdx.x * 256 + threadIdx.x;
    if (idx < 32768) {
        int n = idx >> 7, k = idx & 127;
        float v;
        if (n < 32)       v = gl1_w[n * 128 + k];
        else if (n < 64)  v = l1_w[(n - 64 + 32) * 128 + k];
        else if (n < 96)  v = gl2_w[(n - 64) * 128 + k];
        else if (n < 128) v = l2_w[(n - 96) * 128 + k];
        else              v = eg_w[(n - 128) * 128 + k];
        wcat[idx] = f2bf(v);
    } else if (idx < 32768 + 4096) {
        int i = idx - 32768;
        lasbf[i] = f2bf(las_w[i]);
    }
}

// ---------------- z path ----------------
__global__ __launch_bounds__(256) void k_zproj(
    const float* __restrict__ z, const float* __restrict__ ln_w,
    const u16* __restrict__ wcat,
    const float* __restrict__ l1_b, const float* __restrict__ l2_b,
    const float* __restrict__ eg_b, const float* __restrict__ z_mask,
    u16* __restrict__ ab1, u16* __restrict__ ab2, u16* __restrict__ g)
{
    __shared__ u16 A[128 * 136];
    __shared__ float zms[128];
    const int tid = threadIdx.x;
    const int lane = tid & 63, wave = tid >> 6;
    const int quad = lane >> 4, l15 = lane & 15;
    const int np = blockIdx.x;

    ln_stage_c(z + (size_t)np * 128 * 128, ln_w, A, tid);
    if (tid < 128) zms[tid] = z_mask[np * 128 + tid];
    __syncthreads();

    s8v bfr[4][4];
#pragma unroll
    for (int nt = 0; nt < 4; nt++) {
        int n = wave * 64 + nt * 16 + l15;
#pragma unroll
        for (int kt = 0; kt < 4; kt++)
            bfr[nt][kt] = *(const s8v*)(wcat + n * 128 + kt * 32 + quad * 8);
    }

    f4v acc[8][4];
#pragma unroll
    for (int mt = 0; mt < 8; mt++)
#pragma unroll
        for (int nt = 0; nt < 4; nt++)
            acc[mt][nt] = (f4v){0.f, 0.f, 0.f, 0.f};

#pragma unroll
    for (int kt = 0; kt < 4; kt++) {
#pragma unroll
        for (int mt = 0; mt < 8; mt++) {
            s8v af = *(const s8v*)(A + (mt * 16 + l15) * 136 + kt * 32 + quad * 8);
#pragma unroll
            for (int nt = 0; nt < 4; nt++)
                acc[mt][nt] = mfma16(af, bfr[nt][kt], acc[mt][nt]);
        }
    }

    if (wave < 2) {
        u16* dst = (wave == 0) ? ab1 : ab2;
        const float* bias = (wave == 0) ? l1_b : l2_b;
#pragma unroll
        for (int mt = 0; mt < 8; mt++) {
            int j0 = mt * 16 + quad * 4;
#pragma unroll
            for (int cp = 0; cp < 2; cp++) {
                int c = cp * 16 + l15;
                float bb = bias[c];
                ushort4 o;
#pragma unroll
                for (int r = 0; r < 4; r++) {
                    float a0 = acc[mt][cp][r];
                    float a1 = acc[mt][cp + 2][r];
                    float v = sigmoidf_(a0) * (a1 + bb) * zms[j0 + r];
                    ((u16*)&o)[r] = f2bf(v);
                }
                *(ushort4*)(dst + (size_t)c * 98304 + np * 128 + j0) = o;
            }
        }
    } else {
        int ebase = (wave - 2) * 64;
#pragma unroll
        for (int mt = 0; mt < 8; mt++) {
            int j0 = mt * 16 + quad * 4;
#pragma unroll
            for (int nt = 0; nt < 4; nt++) {
                int e = ebase + nt * 16 + l15;
                float eb = eg_b[e];
#pragma unroll
                for (int r = 0; r < 4; r++) {
                    float v = sigmoidf_(acc[mt][nt][r] + eb);
                    g[((size_t)np * 128 + j0 + r) * 128 + e] = f2bf(v);
                }
            }
        }
    }
}

// ---- generic LN + gated N=64 projection body (shared by pp kernel and merged cp) ----
__device__ __forceinline__ void proj64_body(
    const float* __restrict__ X, const float* __restrict__ ln_w,
    const u16* __restrict__ Wbase, const float* __restrict__ lb,
    u16* __restrict__ out, int nrows, size_t rowbase, u16* __restrict__ A, int tid)
{
    const int lane = tid & 63, wave = tid >> 6;
    const int quad = lane >> 4, l15 = lane & 15;

    ln_stage_c(X + rowbase * 128, ln_w, A, tid);
    __syncthreads();

    s8v bfr[4][4];
#pragma unroll
    for (int nt = 0; nt < 4; nt++) {
        int n = nt * 16 + l15;   // rows 0..31 gate, 32..63 linear
#pragma unroll
        for (int kt = 0; kt < 4; kt++)
            bfr[nt][kt] = *(const s8v*)(Wbase + n * 128 + kt * 32 + quad * 8);
    }

    f4v acc[2][4];
#pragma unroll
    for (int mt = 0; mt < 2; mt++)
#pragma unroll
        for (int nt = 0; nt < 4; nt++)
            acc[mt][nt] = (f4v){0.f, 0.f, 0.f, 0.f};

#pragma unroll
    for (int kt = 0; kt < 4; kt++) {
#pragma unroll
        for (int mt = 0; mt < 2; mt++) {
            s8v af = *(const s8v*)(A + (wave * 32 + mt * 16 + l15) * 136 + kt * 32 + quad * 8);
#pragma unroll
            for (int nt = 0; nt < 4; nt++)
                acc[mt][nt] = mfma16(af, bfr[nt][kt], acc[mt][nt]);
        }
    }

#pragma unroll
    for (int mt = 0; mt < 2; mt++) {
        int k0 = wave * 32 + mt * 16 + quad * 4;
#pragma unroll
        for (int cp = 0; cp < 2; cp++) {
            int c = cp * 16 + l15;
            float bb = lb[c];
            ushort4 o;
#pragma unroll
            for (int r = 0; r < 4; r++) {
                float v = sigmoidf_(acc[mt][cp][r]) * (acc[mt][cp + 2][r] + bb);
                ((u16*)&o)[r] = f2bf(v);
            }
            *(ushort4*)(out + (size_t)c * nrows + rowbase + k0) = o;
        }
    }
}

__global__ __launch_bounds__(256) void k_proj_pp(
    const float* __restrict__ X, const float* __restrict__ ln_w,
    const u16* __restrict__ wcat, const float* __restrict__ l2_b,
    u16* __restrict__ out)
{
    __shared__ u16 A[128 * 136];
    proj64_body(X, ln_w, wcat + 64 * 128, l2_b, out, 589824,
                (size_t)blockIdx.x * 128, A, threadIdx.x);
}

// ---- merged: cp projection (blocks 0..127) + ab1 transpose (blocks 128..319) ----
__global__ __launch_bounds__(256) void k_cp_trans(
    const float* __restrict__ cp, const float* __restrict__ ln_w,
    const u16* __restrict__ wcat, const float* __restrict__ l1_b,
    u16* __restrict__ cpcT,
    const u16* __restrict__ ab1t, u16* __restrict__ ab1T)
{
    __shared__ u16 smem[128 * 136];
    const int tid = threadIdx.x;
    if (blockIdx.x < 128) {
        proj64_body(cp, ln_w, wcat, l1_b, cpcT, 16384,
                    (size_t)blockIdx.x * 128, smem, tid);
        return;
    }
    // transpose ab1t [c][np][nc] -> ab1T [c][nc][np]
    const int bid = blockIdx.x - 128;       // 0..191
    const int c = bid / 6;
    const int np0 = (bid % 6) * 128;
    const size_t sbase = (size_t)c * 98304;
    // phase 1: read rows (np) with ushort4 over nc, scatter into smem[nc][133]
#pragma unroll
    for (int it = 0; it < 16; it++) {
        int idx = it * 256 + tid;
        int r = idx >> 5;               // np row 0..127
        int j4 = (idx & 31) * 4;        // nc col
        ushort4 v = *(const ushort4*)(ab1t + sbase + (size_t)(np0 + r) * 128 + j4);
        smem[(j4 + 0) * 133 + r] = v.x;
        smem[(j4 + 1) * 133 + r] = v.y;
        smem[(j4 + 2) * 133 + r] = v.z;
        smem[(j4 + 3) * 133 + r] = v.w;
    }
    __syncthreads();
    // phase 2: write rows (nc) with ushort4 over np
#pragma unroll
    for (int it = 0; it < 16; it++) {
        int idx = it * 256 + tid;
        int j = idx >> 5;               // nc row
        int r4 = (idx & 31) * 4;        // np col
        ushort4 v;
        v.x = smem[j * 133 + r4 + 0];
        v.y = smem[j * 133 + r4 + 1];
        v.z = smem[j * 133 + r4 + 2];
        v.w = smem[j * 133 + r4 + 3];
        *(ushort4*)(ab1T + sbase + (size_t)j * 768 + np0 + r4) = v;
    }
}

// -------- per-channel triangle matmuls -> bf16 blk --------
__global__ __launch_bounds__(256) void k_block(
    const u16* __restrict__ ppc, const u16* __restrict__ ab1T,
    const u16* __restrict__ ab2, const u16* __restrict__ cpcT,
    u16* __restrict__ blkbf)
{
    __shared__ u16 As[128 * 72];
    __shared__ u16 Bs[128 * 72];
    const int tid = threadIdx.x;
    const int lane = tid & 63, wave = tid >> 6;
    const int quad = lane >> 4, l15 = lane & 15;
    const int it = blockIdx.x;
    const int c = blockIdx.y;
    const int i0 = it * 128;
    const int mh = (wave >> 1) * 64, nh = (wave & 1) * 64;

    f4v acc[4][4];
#pragma unroll
    for (int mt = 0; mt < 4; mt++)
#pragma unroll
        for (int nt = 0; nt < 4; nt++)
            acc[mt][nt] = (f4v){0.f, 0.f, 0.f, 0.f};

    auto stage = [&](const u16* Ab, int astride, const u16* Bb, int bstride, int kb) {
        int row = tid >> 1, half = tid & 1;
        const u16* pa = Ab + (size_t)row * astride + kb + half * 32;
        const u16* pb = Bb + (size_t)row * bstride + kb + half * 32;
        u16* da = As + row * 72 + half * 32;
        u16* db = Bs + row * 72 + half * 32;
#pragma unroll
        for (int q = 0; q < 4; q++) {
            *(uint4*)(da + q * 8) = *(const uint4*)(pa + q * 8);
            *(uint4*)(db + q * 8) = *(const uint4*)(pb + q * 8);
        }
    };
    auto compute = [&]() {
#pragma unroll
        for (int kt = 0; kt < 2; kt++) {
            s8v af[4], bf[4];
#pragma unroll
            for (int mt = 0; mt < 4; mt++)
                af[mt] = *(const s8v*)(As + (mh + mt * 16 + l15) * 72 + kt * 32 + quad * 8);
#pragma unroll
            for (int nt = 0; nt < 4; nt++)
                bf[nt] = *(const s8v*)(Bs + (nh + nt * 16 + l15) * 72 + kt * 32 + quad * 8);
#pragma unroll
            for (int mt = 0; mt < 4; mt++)
#pragma unroll
                for (int nt = 0; nt < 4; nt++)
                    acc[mt][nt] = mfma16(af[mt], bf[nt], acc[mt][nt]);
        }
    };

    const u16* Ab1 = ppc + (size_t)c * 589824 + (size_t)i0 * 768;
    const u16* Bb1 = ab1T + (size_t)c * 98304;
    for (int kb = 0; kb < 768; kb += 64) {
        stage(Ab1, 768, Bb1, 768, kb);
        __syncthreads();
        compute();
        __syncthreads();
    }
    const u16* Ab2 = ab2 + (size_t)c * 98304 + (size_t)i0 * 128;
    const u16* Bb2 = cpcT + (size_t)c * 16384;
    for (int kb = 0; kb < 128; kb += 64) {
        stage(Ab2, 128, Bb2, 128, kb);
        __syncthreads();
        compute();
        __syncthreads();
    }

    u16* ob = blkbf + (size_t)c * 98304;
#pragma unroll
    for (int mt = 0; mt < 4; mt++) {
#pragma unroll
        for (int nt = 0; nt < 4; nt++) {
            int jj = nh + nt * 16 + l15;
#pragma unroll
            for (int r = 0; r < 4; r++) {
                int row = i0 + mh + mt * 16 + quad * 4 + r;
                ob[(size_t)row * 128 + jj] = f2bf(acc[mt][nt][r]);
            }
        }
    }
}

// -------- final: LN over c + C->E matmul fused with g and mask --------
__global__ __launch_bounds__(256) void k_final(
    const u16* __restrict__ blkbf, const u16* __restrict__ g,
    const float* __restrict__ z_mask, const float* __restrict__ lnc_w,
    const u16* __restrict__ lasbf, const float* __restrict__ las_b,
    float* __restrict__ out)
{
    __shared__ float vals[128 * 33];
    __shared__ u16 Abf[128 * 40];
    __shared__ u16 gs[128 * 132];
    __shared__ float zms[128];
    __shared__ float lncs[32];
    const int tid = threadIdx.x;
    const int lane = tid & 63, wave = tid >> 6;
    const int quad = lane >> 4, l15 = lane & 15;
    const int np = blockIdx.x;

    // stage g tile [j][e] coalesced
#pragma unroll
    for (int it = 0; it < 16; it++) {
        int idx = it * 256 + tid;
        int j = idx >> 5;
        int e4 = (idx & 31) * 4;
        *(ushort4*)(gs + j * 132 + e4) =
            *(const ushort4*)(g + ((size_t)np * 128 + j) * 128 + e4);
    }
    // stage blk values transposed to [j][c]
#pragma unroll
    for (int it = 0; it < 16; it++) {
        int idx = it * 256 + tid;
        int c = idx >> 7, j = idx & 127;
        vals[j * 33 + c] = bf2f(blkbf[(size_t)c * 98304 + np * 128 + j]);
    }
    if (tid < 128) zms[tid] = z_mask[np * 128 + tid];
    if (tid < 32) lncs[tid] = lnc_w[tid];
    __syncthreads();

    if (tid < 128) {
        int j = tid;
        float s1 = 0.f, s2 = 0.f;
#pragma unroll
        for (int c = 0; c < 32; c++) { float x = vals[j * 33 + c]; s1 += x; s2 += x * x; }
        float m = s1 * (1.f / 32.f);
        float v = s2 * (1.f / 32.f) - m * m;
        float rstd = rsqrtf(v + 1e-5f);
#pragma unroll
        for (int c = 0; c < 32; c++)
            Abf[j * 40 + c] = f2bf((vals[j * 33 + c] - m) * rstd * lncs[c]);
    }
    __syncthreads();

    s8v bfrg[8];
#pragma unroll
    for (int nt = 0; nt < 8; nt++) {
        int e = nt * 16 + l15;
        bfrg[nt] = *(const s8v*)(lasbf + e * 32 + quad * 8);
    }
    f4v acc[2][8];
#pragma unroll
    for (int mt = 0; mt < 2; mt++)
#pragma unroll
        for (int nt = 0; nt < 8; nt++)
            acc[mt][nt] = (f4v){0.f, 0.f, 0.f, 0.f};
#pragma unroll
    for (int mt = 0; mt < 2; mt++) {
        s8v af = *(const s8v*)(Abf + (wave * 32 + mt * 16 + l15) * 40 + quad * 8);
#pragma unroll
        for (int nt = 0; nt < 8; nt++)
            acc[mt][nt] = mfma16(af, bfrg[nt], acc[mt][nt]);
    }

#pragma unroll
    for (int mt = 0; mt < 2; mt++) {
        int jb = wave * 32 + mt * 16 + quad * 4;
#pragma unroll
        for (int nt = 0; nt < 8; nt++) {
            int e = nt * 16 + l15;
            float eb = las_b[e];
#pragma unroll
            for (int r = 0; r < 4; r++) {
                int j = jb + r;
                float gv = bf2f(gs[j * 132 + e]);
                out[((size_t)np * 128 + j) * 128 + e] = gv * (acc[mt][nt][r] + eb) * zms[j];
            }
        }
    }
}

extern "C" void kernel_launch(void* const* d_in, const int* in_sizes, int n_in,
                              void* d_out, int out_size, void* d_ws, size_t ws_size,
                              hipStream_t stream)
{
    const float* z     = (const float*)d_in[0];
    const float* pp    = (const float*)d_in[1];
    const float* cp    = (const float*)d_in[2];
    const float* zm    = (const float*)d_in[3];
    const float* ln_w  = (const float*)d_in[4];
    const float* lnc_w = (const float*)d_in[5];
    const float* gl1_w = (const float*)d_in[6];
    const float* gl2_w = (const float*)d_in[7];
    const float* l1_w  = (const float*)d_in[8];
    const float* l1_b  = (const float*)d_in[9];
    const float* l2_w  = (const float*)d_in[10];
    const float* l2_b  = (const float*)d_in[11];
    const float* eg_w  = (const float*)d_in[12];
    const float* eg_b  = (const float*)d_in[13];
    const float* las_w = (const float*)d_in[14];
    const float* las_b = (const float*)d_in[15];
    float* out = (float*)d_out;

    char* w = (char*)d_ws;
    u16* ppc  = (u16*)w;  w += (size_t)32 * 768 * 768 * 2;   // 36 MB
    u16* ab1t = (u16*)w;  w += (size_t)32 * 768 * 128 * 2;   // 6 MB  [c][np][nc]
    u16* ab1T = (u16*)w;  w += (size_t)32 * 128 * 768 * 2;   // 6 MB  [c][nc][np]
    u16* ab2  = (u16*)w;  w += (size_t)32 * 768 * 128 * 2;   // 6 MB
    u16* cpcT = (u16*)w;  w += (size_t)32 * 128 * 128 * 2;   // 1 MB
    u16* g    = (u16*)w;  w += (size_t)768 * 128 * 128 * 2;  // 24 MB
    u16* blkbf = (u16*)w; w += (size_t)32 * 768 * 128 * 2;   // 6 MB
    u16* wcat  = (u16*)w; w += (size_t)256 * 128 * 2;        // 64 KB
    u16* lasbf = (u16*)w;                                     // 8 KB

    k_prep<<<144, 256, 0, stream>>>(gl1_w, l1_w, gl2_w, l2_w, eg_w, las_w, wcat, lasbf);
    k_zproj<<<768, 256, 0, stream>>>(z, ln_w, wcat, l1_b, l2_b, eg_b, zm, ab1t, ab2, g);
    k_proj_pp<<<4608, 256, 0, stream>>>(pp, ln_w, wcat, l2_b, ppc);
    k_cp_trans<<<320, 256, 0, stream>>>(cp, ln_w, wcat, l1_b, cpcT, ab1t, ab1T);
    dim3 gb(6, 32);
    k_block<<<gb, 256, 0, stream>>>(ppc, ab1T, ab2, cpcT, blkbf);
    k_final<<<768, 256, 0, stream>>>(blkbf, g, zm, lnc_w, lasbf, las_b, out);
}